// Round 16
// baseline (1344.871 us; speedup 1.0000x reference)
//
#include <hip/hip_runtime.h>

typedef unsigned short u16;
typedef __bf16 bf16x8 __attribute__((ext_vector_type(8)));
typedef float f32x4 __attribute__((ext_vector_type(4)));

#define NB 4
#define NN 256
#define DD 128
#define RNN 262144   // NB*NN*NN

__device__ __forceinline__ u16 f2b(float f) {
    unsigned u = __builtin_bit_cast(unsigned, f);
    unsigned rb = ((u >> 16) & 1u) + 0x7FFFu;
    return (u16)((u + rb) >> 16);
}
__device__ __forceinline__ float b2f(u16 u) {
    return __builtin_bit_cast(float, ((unsigned)u) << 16);
}
__device__ __forceinline__ u16 b16(float f) {
    __bf16 h = (__bf16)f;
    return __builtin_bit_cast(u16, h);
}
__device__ __forceinline__ unsigned pk2(float a, float b) {
    ushort2 r;
    r.x = b16(a); r.y = b16(b);
    return __builtin_bit_cast(unsigned, r);
}

__device__ __forceinline__ void glds16(const void* g, void* l) {
    __builtin_amdgcn_global_load_lds((const __attribute__((address_space(1))) void*)g,
                                     (__attribute__((address_space(3))) void*)l, 16, 0, 0);
}

// ---------------- weight prep ----------------
// sec0: Wq fragment-linear for scores. sec1: Wv plain + biases.
// sec2-5: fragment-linear layouts for fused MLP weights.
__global__ void prep_weights(const float* __restrict__ Wqkv_e, const float* __restrict__ bqkv_e,
                             const float* __restrict__ We1a, const float* __restrict__ We1b,
                             const float* __restrict__ We2a, const float* __restrict__ We2b,
                             u16* wqF, u16* wv, float* bqp, float* bvp,
                             u16* w1f_e1, u16* w2f_e1, u16* w1f_e2, u16* w2f_e2) {
    int l = blockIdx.z, sec = blockIdx.y;
    int idx = blockIdx.x * 256 + threadIdx.x;
    if (sec == 0) {            // WqF: steps kt<2, n<128 (head-packed q cols), K=128
        if (idx < 16384) {
            int kt = idx >> 13;
            int rem = idx & 8191;
            int nb = rem >> 10, ks = (rem >> 9) & 1, ln = (rem >> 3) & 63, j = rem & 7;
            int n = nb * 16 + (ln & 15);
            int k = kt * 64 + ks * 32 + (ln >> 4) * 8 + j;
            int col = (n >> 4) * 48 + (n & 15);
            wqF[l * 16384 + idx] = f2b(Wqkv_e[l * 49152 + k * 384 + col]);
        }
    } else if (sec == 1) {
        if (idx < 16384) {
            int k = idx >> 7, c = idx & 127;
            int col = (c >> 4) * 48 + 32 + (c & 15);
            wv[l * 16384 + k * 128 + c] = f2b(Wqkv_e[l * 49152 + k * 384 + col]);
        }
        if (idx < 128) {
            bqp[l * 128 + idx] = bqkv_e[l * 384 + (idx >> 4) * 48 + (idx & 15)];
            bvp[l * 128 + idx] = bqkv_e[l * 384 + (idx >> 4) * 48 + 32 + (idx & 15)];
        }
    } else if (sec == 2) {     // W1F e1: steps (q,kt) q<4,kt<4
        if (idx < 131072) {
            int step = idx >> 13, q = step >> 2, kt = step & 3;
            int rem = idx & 8191;
            int nb = rem >> 10, ks = (rem >> 9) & 1, ln = (rem >> 3) & 63, j = rem & 7;
            int n = q * 128 + nb * 16 + (ln & 15);
            int k = kt * 64 + ks * 32 + (ln >> 4) * 8 + j;
            w1f_e1[l * 131072 + idx] = f2b(We1a[l * 262144 + k * 512 + n]);
        }
    } else if (sec == 3) {     // W2F e1
        if (idx < 65536) {
            int step = idx >> 13, q = step >> 1, kt2 = step & 1;
            int rem = idx & 8191;
            int cb = rem >> 10, ks = (rem >> 9) & 1, ln = (rem >> 3) & 63, j = rem & 7;
            int c = cb * 16 + (ln & 15);
            int k = q * 128 + kt2 * 64 + ks * 32 + (ln >> 4) * 8 + j;
            w2f_e1[l * 65536 + idx] = f2b(We1b[l * 65536 + k * 128 + c]);
        }
    } else if (sec == 4) {     // W1F e2
        if (idx < 65536) {
            int step = idx >> 13, q = step >> 1, kt = step & 1;
            int rem = idx & 8191;
            int nb = rem >> 10, ks = (rem >> 9) & 1, ln = (rem >> 3) & 63, j = rem & 7;
            int n = q * 128 + nb * 16 + (ln & 15);
            int k = kt * 64 + ks * 32 + (ln >> 4) * 8 + j;
            w1f_e2[l * 65536 + idx] = f2b(We2a[l * 65536 + k * 512 + n]);
        }
    } else {                   // W2F e2
        if (idx < 65536) {
            int step = idx >> 13, q = step >> 1, kt2 = step & 1;
            int rem = idx & 8191;
            int cb = rem >> 10, ks = (rem >> 9) & 1, ln = (rem >> 3) & 63, j = rem & 7;
            int c = cb * 16 + (ln & 15);
            int k = q * 128 + kt2 * 64 + ks * 32 + (ln >> 4) * 8 + j;
            w2f_e2[l * 65536 + idx] = f2b(We2b[l * 65536 + k * 128 + c]);
        }
    }
}

__global__ void init_e(const float4* __restrict__ src, ushort4* __restrict__ dst) {
    const long n4 = 8388608;
    for (long i = (long)blockIdx.x * blockDim.x + threadIdx.x; i < n4; i += (long)gridDim.x * blockDim.x) {
        float4 v = src[i];
        ushort4 o;
        o.x = f2b(v.x); o.y = f2b(v.y); o.z = f2b(v.z); o.w = f2b(v.w);
        dst[i] = o;
    }
}

__global__ void init_n(const float* __restrict__ node, float* __restrict__ nf) {
    int i = blockIdx.x * 256 + threadIdx.x;
    if (i < 131072) nf[i] = node[i];
}

// ---------------- pre_node ----------------
__launch_bounds__(512)
__global__ void pre_node_kernel(const float* __restrict__ nf, const float* __restrict__ We1a,
                                float* __restrict__ preS, float* __restrict__ preT) {
    __shared__ float nr[128];
    int tid = threadIdx.x;
    int row = blockIdx.x;
    if (tid < 128) nr[tid] = nf[(long)row * 128 + tid];
    __syncthreads();
    int c = tid;
    float s = 0.f, t = 0.f;
    const float* Ws = We1a + (long)256 * 512 + c;
    const float* Wt = We1a + (long)384 * 512 + c;
    #pragma unroll 8
    for (int k = 0; k < 128; ++k) {
        float nv = nr[k];
        s += nv * Ws[k * 512];
        t += nv * Wt[k * 512];
    }
    preS[(long)row * 512 + c] = s;
    preT[(long)row * 512 + c] = t;
}

// ---------------- K1: qn/vn ----------------
__global__ void qkvn_kernel(const float* __restrict__ nf, const float* __restrict__ W,
                            const float* __restrict__ bias, float* __restrict__ qn, float* __restrict__ vn) {
    __shared__ float nr[128];
    int tid = threadIdx.x;
    int row = blockIdx.x;
    if (tid < 128) nr[tid] = nf[(long)row * 128 + tid];
    __syncthreads();
    int c = tid & 127;
    bool isq = tid < 128;
    int col = (c >> 4) * 48 + (c & 15) + (isq ? 0 : 32);
    float a = bias[col];
    #pragma unroll 8
    for (int k = 0; k < 128; ++k) a += nr[k] * W[k * 384 + col];
    if (isq) qn[(long)row * 128 + c] = a;
    else     vn[(long)row * 128 + c] = a;
}

// ---------------- K2: scores (A via LDS, Wq fragments global->VGPR) ----------------
__launch_bounds__(256, 2)
__global__ void scores_kernel(const u16* __restrict__ ein, const u16* __restrict__ WqF,
                              const float* __restrict__ bqp, const float* __restrict__ qn,
                              float* __restrict__ scoresp) {
    __shared__ u16 As[128 * 64];
    int tid = threadIdx.x;
    int wid = tid >> 6, lane = tid & 63;
    int bid = blockIdx.x;
    int jhalf = bid & 1, bi = bid >> 1;
    int b = bi >> 8, i = bi & 255;
    int wr = wid >> 1, wc = wid & 1;

    f32x4 acc[4][4];
    f32x4 z = {0.f, 0.f, 0.f, 0.f};
    #pragma unroll
    for (int m = 0; m < 4; ++m)
        #pragma unroll
        for (int n = 0; n < 4; ++n) acc[m][n] = z;

    const u16* wq = WqF + (wc * 4) * 1024 + lane * 8;
    const long arow0 = ((long)(b * NN + i) * NN + jhalf * 128);
    for (int kt = 0; kt < 2; ++kt) {
        int k0 = kt << 6;
        #pragma unroll
        for (int p = 0; p < 4; ++p) {
            int r = p * 32 + (tid >> 3);
            int ch = tid & 7;
            const u16* src = ein + (arow0 + r) * 128 + k0 + ((ch ^ (r & 7)) << 3);
            glds16(src, (char*)As + (p << 12) + (wid << 10));
        }
        __syncthreads();
        #pragma unroll
        for (int ks = 0; ks < 2; ++ks) {
            bf16x8 af[4], bfr[4];
            #pragma unroll
            for (int m = 0; m < 4; ++m) {
                int r = wr * 64 + m * 16 + (lane & 15);
                int ch = (ks * 4 + (lane >> 4)) ^ (r & 7);
                af[m] = *reinterpret_cast<const bf16x8*>(&As[r * 64 + ch * 8]);
            }
            #pragma unroll
            for (int n = 0; n < 4; ++n)
                bfr[n] = *reinterpret_cast<const bf16x8*>(wq + kt * 8192 + n * 1024 + ks * 512);
            #pragma unroll
            for (int m = 0; m < 4; ++m)
                #pragma unroll
                for (int n = 0; n < 4; ++n)
                    acc[m][n] = __builtin_amdgcn_mfma_f32_16x16x32_bf16(af[m], bfr[n], acc[m][n], 0, 0, 0);
        }
        __syncthreads();
    }
    const float* qnb = qn + (long)(b * NN + i) * 128;
    #pragma unroll
    for (int m = 0; m < 4; ++m) {
        #pragma unroll
        for (int n = 0; n < 4; ++n) {
            int col = wc * 64 + n * 16 + (lane & 15);
            float add = bqp[col] + qnb[col];
            float sv[4];
            #pragma unroll
            for (int t = 0; t < 4; ++t) { float qv = acc[m][n][t] + add; sv[t] = qv * qv; }
            #pragma unroll
            for (int mk = 1; mk <= 8; mk <<= 1)
                #pragma unroll
                for (int t = 0; t < 4; ++t) sv[t] += __shfl_xor(sv[t], mk);
            if ((lane & 15) == 0) {
                int head = wc * 4 + n;
                int jb = jhalf * 128 + wr * 64 + m * 16 + ((lane >> 4) << 2);
                long sbase = ((long)(b * 8 + head) * 256 + i) * 256 + jb;
                #pragma unroll
                for (int t = 0; t < 4; ++t) scoresp[sbase + t] = sv[t] * 0.25f;
            }
        }
    }
}

// ---------------- K3: softmax + factored PV ----------------
__launch_bounds__(256)
__global__ void attn_pv_kernel(const float* __restrict__ scoresp, const u16* __restrict__ ein,
                               const float* __restrict__ vn, const u16* __restrict__ Wv,
                               const float* __restrict__ bvp, float* __restrict__ attn_o) {
    __shared__ float s_s[8 * 256];
    __shared__ float g_s[8 * 128];
    __shared__ float part[256];
    int tid = threadIdx.x;
    int b = blockIdx.x >> 8, i = blockIdx.x & 255;
    for (int v = tid; v < 2048; v += 256) {
        int h = v >> 8, j = v & 255;
        s_s[v] = scoresp[((long)(b * 8 + h) * 256 + i) * 256 + j];
    }
    __syncthreads();
    {
        int h = tid >> 5, lg = tid & 31;
        float vals[8], mx = -1e30f;
        #pragma unroll
        for (int t = 0; t < 8; ++t) { vals[t] = s_s[h * 256 + lg + t * 32]; mx = fmaxf(mx, vals[t]); }
        #pragma unroll
        for (int mk = 16; mk; mk >>= 1) mx = fmaxf(mx, __shfl_xor(mx, mk));
        float sum = 0.f;
        #pragma unroll
        for (int t = 0; t < 8; ++t) { vals[t] = __expf(vals[t] - mx); sum += vals[t]; }
        #pragma unroll
        for (int mk = 16; mk; mk >>= 1) sum += __shfl_xor(sum, mk);
        float inv = 1.f / sum;
        #pragma unroll
        for (int t = 0; t < 8; ++t) s_s[h * 256 + lg + t * 32] = vals[t] * inv;
    }
    __syncthreads();
    {
        int k = tid & 127, h0 = tid >> 7;
        const u16* erow = ein + ((long)(b * NN + i) * NN) * 128 + k;
        float a0 = 0, a1 = 0, a2 = 0, a3 = 0;
        for (int j = 0; j < 256; ++j) {
            float ev = b2f(erow[(long)j * 128]);
            a0 += s_s[(h0    ) * 256 + j] * ev;
            a1 += s_s[(h0 + 2) * 256 + j] * ev;
            a2 += s_s[(h0 + 4) * 256 + j] * ev;
            a3 += s_s[(h0 + 6) * 256 + j] * ev;
        }
        g_s[(h0    ) * 128 + k] = a0;
        g_s[(h0 + 2) * 128 + k] = a1;
        g_s[(h0 + 4) * 128 + k] = a2;
        g_s[(h0 + 6) * 128 + k] = a3;
    }
    __syncthreads();
    {
        int c = tid & 127, half = tid >> 7;
        int h = c >> 4;
        float a = 0.f;
        for (int j = half * 128; j < half * 128 + 128; ++j)
            a += s_s[h * 256 + j] * vn[((long)(b * NN + j)) * 128 + c];
        for (int k = half * 64; k < half * 64 + 64; ++k)
            a += g_s[h * 128 + k] * b2f(Wv[k * 128 + c]);
        part[tid] = a;
    }
    __syncthreads();
    if (tid < 128)
        attn_o[((long)(b * NN + i)) * 128 + tid] = part[tid] + part[128 + tid] + bvp[tid];
}

// ---------------- K4: node path (split-k on the two long serial chains) ----------------
__launch_bounds__(256)
__global__ void node_kernel(const float* __restrict__ attn_o, float* __restrict__ nf,
                            const float* __restrict__ Wo, const float* __restrict__ bo,
                            const float* __restrict__ Wn1, const float* __restrict__ bn1,
                            const float* __restrict__ Wn2, const float* __restrict__ bn2,
                            const float* __restrict__ g1, const float* __restrict__ b1,
                            const float* __restrict__ g2, const float* __restrict__ b2) {
    __shared__ float ao[128], nr[128], n1[128], hb[512];
    __shared__ float part[256];
    __shared__ float red[8];
    int tid = threadIdx.x;
    int wid = tid >> 6, lane = tid & 63;
    long base = (long)blockIdx.x * 128;
    if (tid < 128) { ao[tid] = attn_o[base + tid]; nr[tid] = nf[base + tid]; }
    __syncthreads();
    {   // Wo proj: split k across both halves
        int c = tid & 127, half = tid >> 7;
        float a = 0.f;
        #pragma unroll 8
        for (int k = half * 64; k < half * 64 + 64; ++k) a += ao[k] * Wo[k * 128 + c];
        part[tid] = a;
    }
    __syncthreads();
    float x = 0.f;
    if (tid < 128) x = nr[tid] + bo[tid] + part[tid] + part[128 + tid];
    float s = (tid < 128) ? x : 0.f, q = (tid < 128) ? x * x : 0.f;
    #pragma unroll
    for (int mk = 1; mk <= 32; mk <<= 1) { s += __shfl_xor(s, mk); q += __shfl_xor(q, mk); }
    if (lane == 0) { red[wid * 2] = s; red[wid * 2 + 1] = q; }
    __syncthreads();
    float sum = red[0] + red[2] + red[4] + red[6];
    float sq  = red[1] + red[3] + red[5] + red[7];
    float mean = sum * (1.f / 128.f);
    float var = sq * (1.f / 128.f) - mean * mean;
    float rs = rsqrtf(var + 1e-5f);
    __syncthreads();
    if (tid < 128) n1[tid] = (x - mean) * rs * g1[tid] + b1[tid];
    __syncthreads();
    for (int c = tid; c < 512; c += 256) {
        float a = bn1[c];
        #pragma unroll 8
        for (int k = 0; k < 128; ++k) a += n1[k] * Wn1[k * 512 + c];
        hb[c] = a > 0.f ? a : 0.f;
    }
    __syncthreads();
    {   // Wn2 proj: split k (512) across both halves
        int c = tid & 127, half = tid >> 7;
        float a = 0.f;
        #pragma unroll 8
        for (int k = half * 256; k < half * 256 + 256; ++k) a += hb[k] * Wn2[k * 128 + c];
        part[tid] = a;
    }
    __syncthreads();
    float y = 0.f;
    if (tid < 128) y = n1[tid] + bn2[tid] + part[tid] + part[128 + tid];
    float s2 = (tid < 128) ? y : 0.f, q2 = (tid < 128) ? y * y : 0.f;
    #pragma unroll
    for (int mk = 1; mk <= 32; mk <<= 1) { s2 += __shfl_xor(s2, mk); q2 += __shfl_xor(q2, mk); }
    if (lane == 0) { red[wid * 2] = s2; red[wid * 2 + 1] = q2; }
    __syncthreads();
    sum = red[0] + red[2] + red[4] + red[6];
    sq  = red[1] + red[3] + red[5] + red[7];
    mean = sum * (1.f / 128.f);
    var = sq * (1.f / 128.f) - mean * mean;
    rs = rsqrtf(var + 1e-5f);
    if (tid < 128) {
        float o = (y - mean) * rs * g2[tid] + b2[tid];
        nf[base + tid] = o;
    }
}

// ---------------- fused edge-MLP v10: R8 structure + 4-buffer weight rotation (2-phase prefetch) ----------------
// eout = LN2(em + relu(em@We2a+b)@We2b + b), em = LN1(e + relu(cat@We1a+pre)@We1b + b).
__launch_bounds__(256, 3)
__global__ void fused_mlp6(const u16* __restrict__ W1aF, const float* __restrict__ b1a,
                           const u16* __restrict__ W1bF, const float* __restrict__ b1b,
                           const u16* __restrict__ W2aF, const float* __restrict__ b2a,
                           const u16* __restrict__ W2bF, const float* __restrict__ b2b,
                           const u16* __restrict__ ein,
                           const float* __restrict__ preS, const float* __restrict__ preT,
                           const float* __restrict__ ln1g, const float* __restrict__ ln1b,
                           const float* __restrict__ ln2g, const float* __restrict__ ln2b,
                           u16* __restrict__ e_dst) {
    __shared__ __align__(16) u16 A_lds[16384];   // 4 regions x 4096 u16: 0,1 = e(i,j); 2,3 = e(j,i) -> e_mid
    __shared__ __align__(16) u16 Hs[8192];       // 16KB H tile [64r][128n] chunk-swizzled
    __shared__ float psum[256], psq[256];

    int tid = threadIdx.x;
    int wid = tid >> 6, lane = tid & 63;
    long row0 = (long)blockIdx.x * 64;
    int b = (int)(row0 >> 16);
    int rem0 = (int)(row0 & 65535);
    int i_ = rem0 >> 8, j0 = rem0 & 255;

    #pragma unroll
    for (int kt = 0; kt < 4; ++kt)
        #pragma unroll
        for (int pp = 0; pp < 2; ++pp) {
            int r = pp * 32 + (tid >> 3);
            int ch = tid & 7;
            long ridx = (kt < 2) ? (long)(b * NN + i_) * NN + (j0 + r)
                                 : (long)(b * NN + (j0 + r)) * NN + i_;
            const u16* src = ein + ridx * DD + ((kt & 1) << 6) + ((ch ^ (r & 7)) << 3);
            glds16(src, (char*)A_lds + kt * 8192 + (pp << 12) + (wid << 10));
        }
    asm volatile("s_waitcnt vmcnt(0)" ::: "memory");
    __builtin_amdgcn_sched_barrier(0);
    __builtin_amdgcn_s_barrier();
    __builtin_amdgcn_sched_barrier(0);

    const u16* w1a = W1aF + (wid * 2) * 1024 + lane * 8;
    const u16* w1b = W1bF + (wid * 2) * 1024 + lane * 8;
    const u16* w2a = W2aF + (wid * 2) * 1024 + lane * 8;
    const u16* w2b = W2bF + (wid * 2) * 1024 + lane * 8;

    f32x4 z = {0.f, 0.f, 0.f, 0.f};
    f32x4 acc1[2][4], acc2[4][2];
    bf16x8 afA[4], afB[4], afC[4], afD[4], g2A[4], g2B[4];

    auto FR4 = [&](bf16x8 (&d)[4], const u16* base, int step) {
        const u16* p = base + (step << 13);
        d[0] = *reinterpret_cast<const bf16x8*>(p);
        d[1] = *reinterpret_cast<const bf16x8*>(p + 1024);
        d[2] = *reinterpret_cast<const bf16x8*>(p + 512);
        d[3] = *reinterpret_cast<const bf16x8*>(p + 1536);
    };
    auto G1K = [&](bf16x8 (&cur)[4], int reg) {
        #pragma unroll
        for (int ks = 0; ks < 2; ++ks) {
            bf16x8 bfr[4];
            #pragma unroll
            for (int rf = 0; rf < 4; ++rf) {
                int r = rf * 16 + (lane & 15);
                int ch = (ks * 4 + (lane >> 4)) ^ (r & 7);
                bfr[rf] = *reinterpret_cast<const bf16x8*>(&A_lds[reg * 4096 + r * 64 + ch * 8]);
            }
            #pragma unroll
            for (int mn = 0; mn < 2; ++mn)
                #pragma unroll
                for (int rf = 0; rf < 4; ++rf)
                    acc1[mn][rf] = __builtin_amdgcn_mfma_f32_16x16x32_bf16(cur[ks * 2 + mn], bfr[rf], acc1[mn][rf], 0, 0, 0);
        }
    };
    auto G2K = [&](bf16x8 (&w)[4], int kt2) {
        #pragma unroll
        for (int ks = 0; ks < 2; ++ks) {
            bf16x8 af2[4];
            #pragma unroll
            for (int rf = 0; rf < 4; ++rf) {
                int r = rf * 16 + (lane & 15);
                int c8 = kt2 * 8 + ks * 4 + (lane >> 4);
                int cs = (c8 & 8) | ((c8 ^ r) & 7);
                af2[rf] = *reinterpret_cast<const bf16x8*>((const char*)Hs + r * 256 + cs * 16);
            }
            #pragma unroll
            for (int rf = 0; rf < 4; ++rf)
                #pragma unroll
                for (int cf = 0; cf < 2; ++cf)
                    acc2[rf][cf] = __builtin_amdgcn_mfma_f32_16x16x32_bf16(af2[rf], w[ks * 2 + cf], acc2[rf][cf], 0, 0, 0);
        }
    };
    auto EPI = [&](int q, const float* bias, bool wp) {
        #pragma unroll
        for (int mn = 0; mn < 2; ++mn) {
            int nl0 = wid * 32 + mn * 16 + ((lane >> 4) << 2);
            int n0g = (q << 7) + nl0;
            float4 bb = *reinterpret_cast<const float4*>(&bias[n0g]);
            if (wp) {
                float4 pt = *reinterpret_cast<const float4*>(&preT[(long)(b * NN + i_) * 512 + n0g]);
                bb.x += pt.x; bb.y += pt.y; bb.z += pt.z; bb.w += pt.w;
            }
            #pragma unroll
            for (int rf = 0; rf < 4; ++rf) {
                int r = rf * 16 + (lane & 15);
                float b0 = bb.x, b1_ = bb.y, b2_ = bb.z, b3 = bb.w;
                if (wp) {
                    float4 ps = *reinterpret_cast<const float4*>(&preS[(long)(b * NN + j0 + r) * 512 + n0g]);
                    b0 += ps.x; b1_ += ps.y; b2_ += ps.z; b3 += ps.w;
                }
                float v0 = acc1[mn][rf][0] + b0; v0 = v0 > 0.f ? v0 : 0.f;
                float v1 = acc1[mn][rf][1] + b1_; v1 = v1 > 0.f ? v1 : 0.f;
                float v2 = acc1[mn][rf][2] + b2_; v2 = v2 > 0.f ? v2 : 0.f;
                float v3 = acc1[mn][rf][3] + b3; v3 = v3 > 0.f ? v3 : 0.f;
                uint2 pk;
                pk.x = pk2(v0, v1);
                pk.y = pk2(v2, v3);
                int c8 = nl0 >> 3;
                int cs = (c8 & 8) | ((c8 ^ r) & 7);
                *reinterpret_cast<uint2*>((char*)Hs + r * 256 + cs * 16 + (nl0 & 7) * 2) = pk;
            }
        }
    };
    auto LNA = [&](const float* bias, int rb) {
        #pragma unroll
        for (int rf = 0; rf < 4; ++rf) {
            float sv[4] = {0.f, 0.f, 0.f, 0.f}, qv[4] = {0.f, 0.f, 0.f, 0.f};
            #pragma unroll
            for (int cf = 0; cf < 2; ++cf) {
                int c = wid * 32 + cf * 16 + (lane & 15);
                float bb = bias[c];
                int kk = c & 63, kreg = rb + (c >> 6);
                #pragma unroll
                for (int t = 0; t < 4; ++t) {
                    int r = rf * 16 + ((lane >> 4) << 2) + t;
                    float er = b2f(A_lds[kreg * 4096 + r * 64 + (((kk >> 3) ^ (r & 7)) << 3) + (kk & 7)]);
                    float x = acc2[rf][cf][t] + bb + er;
                    acc2[rf][cf][t] = x;
                    sv[t] += x;
                    qv[t] += x * x;
                }
            }
            #pragma unroll
            for (int mk = 1; mk <= 8; mk <<= 1)
                #pragma unroll
                for (int t = 0; t < 4; ++t) { sv[t] += __shfl_xor(sv[t], mk); qv[t] += __shfl_xor(qv[t], mk); }
            if ((lane & 15) == 0) {
                #pragma unroll
                for (int t = 0; t < 4; ++t) {
                    int r = rf * 16 + ((lane >> 4) << 2) + t;
                    psum[r * 4 + wid] = sv[t];
                    psq[r * 4 + wid] = qv[t];
                }
            }
        }
    };

    // ============================= MLP1 =============================
    #pragma unroll
    for (int rf = 0; rf < 4; ++rf) { acc2[rf][0] = z; acc2[rf][1] = z; }
    FR4(afA, w1a, 0);
    FR4(afB, w1a, 1);
    for (int q = 0; q < 4; ++q) {
        #pragma unroll
        for (int mn = 0; mn < 2; ++mn)
            #pragma unroll
            for (int rf = 0; rf < 4; ++rf) acc1[mn][rf] = z;
        FR4(afC, w1a, q * 4 + 2); G1K(afA, 0);
        FR4(afD, w1a, q * 4 + 3); G1K(afB, 1);
        FR4(g2A, w1b, q * 2 + 0); G1K(afC, 2);
        FR4(g2B, w1b, q * 2 + 1); G1K(afD, 3);
        if (q) {
            __builtin_amdgcn_sched_barrier(0);
            __builtin_amdgcn_s_barrier();
            __builtin_amdgcn_sched_barrier(0);
        }
        EPI(q, b1a, true);
        asm volatile("s_waitcnt lgkmcnt(0)" ::: "memory");
        __builtin_amdgcn_sched_barrier(0);
        __builtin_amdgcn_s_barrier();
        __builtin_amdgcn_sched_barrier(0);
        if (q < 3) FR4(afA, w1a, (q + 1) * 4);
        G2K(g2A, 0);
        if (q < 3) FR4(afB, w1a, (q + 1) * 4 + 1);
        G2K(g2B, 1);
    }

    // ---- prefetch MLP2's first two weight tiles (hidden under LN1) ----
    FR4(afA, w2a, 0);
    FR4(afB, w2a, 1);

    // ---- LN1 -> e_mid into regions 2,3 ----
    LNA(b1b, 0);
    __syncthreads();
    #pragma unroll
    for (int rf = 0; rf < 4; ++rf) {
        #pragma unroll
        for (int t = 0; t < 4; ++t) {
            int r = rf * 16 + ((lane >> 4) << 2) + t;
            float sum = psum[r * 4] + psum[r * 4 + 1] + psum[r * 4 + 2] + psum[r * 4 + 3];
            float sq  = psq[r * 4] + psq[r * 4 + 1] + psq[r * 4 + 2] + psq[r * 4 + 3];
            float mean = sum * (1.f / 128.f);
            float var = sq * (1.f / 128.f) - mean * mean;
            float rs = rsqrtf(var + 1e-5f);
            #pragma unroll
            for (int cf = 0; cf < 2; ++cf) {
                int c = wid * 32 + cf * 16 + (lane & 15);
                float o = (acc2[rf][cf][t] - mean) * rs * ln1g[c] + ln1b[c];
                int kk = c & 63;
                A_lds[(2 + (c >> 6)) * 4096 + r * 64 + (((kk >> 3) ^ (r & 7)) << 3) + (kk & 7)] = b16(o);
            }
        }
    }
    __syncthreads();

    // ============================= MLP2 =============================
    #pragma unroll
    for (int rf = 0; rf < 4; ++rf) { acc2[rf][0] = z; acc2[rf][1] = z; }
    for (int q = 0; q < 4; ++q) {
        #pragma unroll
        for (int mn = 0; mn < 2; ++mn)
            #pragma unroll
            for (int rf = 0; rf < 4; ++rf) acc1[mn][rf] = z;
        FR4(g2A, w2b, q * 2 + 0); G1K(afA, 2);
        FR4(g2B, w2b, q * 2 + 1); G1K(afB, 3);
        if (q) {
            __builtin_amdgcn_sched_barrier(0);
            __builtin_amdgcn_s_barrier();
            __builtin_amdgcn_sched_barrier(0);
        }
        EPI(q, b2a, false);
        asm volatile("s_waitcnt lgkmcnt(0)" ::: "memory");
        __builtin_amdgcn_sched_barrier(0);
        __builtin_amdgcn_s_barrier();
        __builtin_amdgcn_sched_barrier(0);
        if (q < 3) FR4(afA, w2a, (q + 1) * 2);
        G2K(g2A, 0);
        if (q < 3) FR4(afB, w2a, (q + 1) * 2 + 1);
        G2K(g2B, 1);
    }

    // ---- LN2 (e_res = e_mid, regions 2,3) -> repack into regions 0,1 linear ----
    LNA(b2b, 2);
    __syncthreads();
    #pragma unroll
    for (int rf = 0; rf < 4; ++rf) {
        #pragma unroll
        for (int t = 0; t < 4; ++t) {
            int r = rf * 16 + ((lane >> 4) << 2) + t;
            float sum = psum[r * 4] + psum[r * 4 + 1] + psum[r * 4 + 2] + psum[r * 4 + 3];
            float sq  = psq[r * 4] + psq[r * 4 + 1] + psq[r * 4 + 2] + psq[r * 4 + 3];
            float mean = sum * (1.f / 128.f);
            float var = sq * (1.f / 128.f) - mean * mean;
            float rs = rsqrtf(var + 1e-5f);
            #pragma unroll
            for (int cf = 0; cf < 2; ++cf) {
                int c = wid * 32 + cf * 16 + (lane & 15);
                float o = (acc2[rf][cf][t] - mean) * rs * ln2g[c] + ln2b[c];
                A_lds[r * 128 + c] = b16(o);
            }
        }
    }
    __syncthreads();
    #pragma unroll
    for (int pp = 0; pp < 4; ++pp) {
        ulonglong2 v = *reinterpret_cast<const ulonglong2*>((char*)A_lds + (pp << 12) + tid * 16);
        *reinterpret_cast<ulonglong2*>((char*)e_dst + row0 * 256 + (pp << 12) + tid * 16) = v;
    }
}

extern "C" void kernel_launch(void* const* d_in, const int* in_sizes, int n_in,
                              void* d_out, int out_size, void* d_ws, size_t ws_size,
                              hipStream_t stream) {
    (void)in_sizes; (void)n_in; (void)out_size; (void)ws_size;
    const float* node   = (const float*)d_in[0];
    const float* edge   = (const float*)d_in[1];
    const float* Wqkv_n = (const float*)d_in[2];
    const float* bqkv_n = (const float*)d_in[3];
    const float* Wqkv_e = (const float*)d_in[4];
    const float* bqkv_e = (const float*)d_in[5];
    const float* Wo     = (const float*)d_in[6];
    const float* bo     = (const float*)d_in[7];
    const float* Wn1    = (const float*)d_in[8];
    const float* bn1    = (const float*)d_in[9];
    const float* Wn2    = (const float*)d_in[10];
    const float* bn2    = (const float*)d_in[11];
    const float* ln1n_g = (const float*)d_in[12];
    const float* ln1n_b = (const float*)d_in[13];
    const float* ln2n_g = (const float*)d_in[14];
    const float* ln2n_b = (const float*)d_in[15];
    const float* We1a   = (const float*)d_in[16];
    const float* be1a   = (const float*)d_in[17];
    const float* We1b   = (const float*)d_in[18];
    const float* be1b   = (const float*)d_in[19];
    const float* We2a   = (const float*)d_in[20];
    const float* be2a   = (const float*)d_in[21];
    const float* We2b   = (const float*)d_in[22];
    const float* be2b   = (const float*)d_in[23];
    const float* ln1e_g = (const float*)d_in[24];
    const float* ln1e_b = (const float*)d_in[25];
    const float* ln2e_g = (const float*)d_in[26];
    const float* ln2e_b = (const float*)d_in[27];

    size_t off = 0;
    char* wsb = (char*)d_ws;
    auto alloc = [&](size_t bytes) -> void* {
        void* p = wsb + off;
        off = (off + bytes + 255) & ~(size_t)255;
        return p;
    };
    u16* eb0      = (u16*)alloc((size_t)RNN * 128 * 2);
    u16* eb1      = (u16*)alloc((size_t)RNN * 128 * 2);
    float* scoresp= (float*)alloc((size_t)2097152 * 4);
    float* qn     = (float*)alloc(131072 * 4);
    float* vn     = (float*)alloc(131072 * 4);
    float* attn_o = (float*)alloc(131072 * 4);
    float* nf     = (float*)alloc(131072 * 4);
    float* preS   = (float*)alloc((size_t)1024 * 512 * 4);
    float* preT   = (float*)alloc((size_t)1024 * 512 * 4);
    u16* wqF      = (u16*)alloc(3 * 16384 * 2);
    u16* wv       = (u16*)alloc(3 * 16384 * 2);
    float* bqp    = (float*)alloc(3 * 128 * 4);
    float* bvp    = (float*)alloc(3 * 128 * 4);
    u16* w1f_e1   = (u16*)alloc(3 * 131072ull * 2);
    u16* w2f_e1   = (u16*)alloc(3 * 65536 * 2);
    u16* w1f_e2   = (u16*)alloc(3 * 65536 * 2);
    u16* w2f_e2   = (u16*)alloc(3 * 65536 * 2);

    {
        dim3 g(512, 6, 3);
        prep_weights<<<g, 256, 0, stream>>>(Wqkv_e, bqkv_e, We1a, We1b, We2a, We2b,
                                            wqF, wv, bqp, bvp, w1f_e1, w2f_e1, w1f_e2, w2f_e2);
    }
    init_e<<<2048, 256, 0, stream>>>((const float4*)edge, (ushort4*)eb0);
    init_n<<<512, 256, 0, stream>>>(node, nf);

    for (int l = 0; l < 3; ++l) {
        u16* ein  = (l & 1) ? eb1 : eb0;
        u16* eout = (l & 1) ? eb0 : eb1;
        qkvn_kernel<<<1024, 256, 0, stream>>>(nf, Wqkv_n + l * 49152, bqkv_n + l * 384, qn, vn);
        scores_kernel<<<2048, 256, 0, stream>>>(ein, wqF + l * 16384, bqp + l * 128, qn, scoresp);
        attn_pv_kernel<<<1024, 256, 0, stream>>>(scoresp, ein, vn, wv + l * 16384, bvp + l * 128, attn_o);
        node_kernel<<<1024, 256, 0, stream>>>(attn_o, nf,
                                              Wo + l * 16384, bo + l * 128,
                                              Wn1 + l * 65536, bn1 + l * 512,
                                              Wn2 + l * 65536, bn2 + l * 128,
                                              ln1n_g + l * 128, ln1n_b + l * 128,
                                              ln2n_g + l * 128, ln2n_b + l * 128);
        pre_node_kernel<<<1024, 512, 0, stream>>>(nf, We1a + (size_t)l * 262144, preS, preT);
        fused_mlp6<<<4096, 256, 0, stream>>>(w1f_e1 + l * 131072, be1a + l * 512,
                                             w2f_e1 + l * 65536, be1b + l * 128,
                                             w1f_e2 + l * 65536, be2a + l * 512,
                                             w2f_e2 + l * 65536, be2b + l * 128,
                                             ein, preS, preT,
                                             ln1e_g + l * 128, ln1e_b + l * 128,
                                             ln2e_g + l * 128, ln2e_b + l * 128,
                                             eout);
    }
    hipMemcpyAsync(d_out, nf, 131072 * sizeof(float), hipMemcpyDeviceToDevice, stream);
}

// Round 17
// 1253.156 us; speedup vs baseline: 1.0732x; 1.0732x over previous
//
#include <hip/hip_runtime.h>

typedef unsigned short u16;
typedef __bf16 bf16x8 __attribute__((ext_vector_type(8)));
typedef float f32x4 __attribute__((ext_vector_type(4)));

#define NB 4
#define NN 256
#define DD 128
#define RNN 262144   // NB*NN*NN

__device__ __forceinline__ u16 f2b(float f) {
    unsigned u = __builtin_bit_cast(unsigned, f);
    unsigned rb = ((u >> 16) & 1u) + 0x7FFFu;
    return (u16)((u + rb) >> 16);
}
__device__ __forceinline__ float b2f(u16 u) {
    return __builtin_bit_cast(float, ((unsigned)u) << 16);
}
__device__ __forceinline__ u16 b16(float f) {
    __bf16 h = (__bf16)f;
    return __builtin_bit_cast(u16, h);
}
__device__ __forceinline__ unsigned pk2(float a, float b) {
    ushort2 r;
    r.x = b16(a); r.y = b16(b);
    return __builtin_bit_cast(unsigned, r);
}

__device__ __forceinline__ void glds16(const void* g, void* l) {
    __builtin_amdgcn_global_load_lds((const __attribute__((address_space(1))) void*)g,
                                     (__attribute__((address_space(3))) void*)l, 16, 0, 0);
}

// ---------------- weight prep ----------------
// sec0: Wq fragment-linear for scores. sec1: Wv plain + biases.
// sec2-5: fragment-linear layouts for fused MLP weights.
// Fragment layout: frag (16n x 32k) = 1KB contiguous, elem addr =
// step*8192 + nb*1024 + ks*512 + lane*8 + j.
__global__ void prep_weights(const float* __restrict__ Wqkv_e, const float* __restrict__ bqkv_e,
                             const float* __restrict__ We1a, const float* __restrict__ We1b,
                             const float* __restrict__ We2a, const float* __restrict__ We2b,
                             u16* wqF, u16* wv, float* bqp, float* bvp,
                             u16* w1f_e1, u16* w2f_e1, u16* w1f_e2, u16* w2f_e2) {
    int l = blockIdx.z, sec = blockIdx.y;
    int idx = blockIdx.x * 256 + threadIdx.x;
    if (sec == 0) {            // WqF: steps kt<2, n<128 (head-packed q cols), K=128
        if (idx < 16384) {
            int kt = idx >> 13;
            int rem = idx & 8191;
            int nb = rem >> 10, ks = (rem >> 9) & 1, ln = (rem >> 3) & 63, j = rem & 7;
            int n = nb * 16 + (ln & 15);
            int k = kt * 64 + ks * 32 + (ln >> 4) * 8 + j;
            int col = (n >> 4) * 48 + (n & 15);
            wqF[l * 16384 + idx] = f2b(Wqkv_e[l * 49152 + k * 384 + col]);
        }
    } else if (sec == 1) {
        if (idx < 16384) {
            int k = idx >> 7, c = idx & 127;
            int col = (c >> 4) * 48 + 32 + (c & 15);
            wv[l * 16384 + k * 128 + c] = f2b(Wqkv_e[l * 49152 + k * 384 + col]);
        }
        if (idx < 128) {
            bqp[l * 128 + idx] = bqkv_e[l * 384 + (idx >> 4) * 48 + (idx & 15)];
            bvp[l * 128 + idx] = bqkv_e[l * 384 + (idx >> 4) * 48 + 32 + (idx & 15)];
        }
    } else if (sec == 2) {     // W1F e1: steps (q,kt) q<4,kt<4
        if (idx < 131072) {
            int step = idx >> 13, q = step >> 2, kt = step & 3;
            int rem = idx & 8191;
            int nb = rem >> 10, ks = (rem >> 9) & 1, ln = (rem >> 3) & 63, j = rem & 7;
            int n = q * 128 + nb * 16 + (ln & 15);
            int k = kt * 64 + ks * 32 + (ln >> 4) * 8 + j;
            w1f_e1[l * 131072 + idx] = f2b(We1a[l * 262144 + k * 512 + n]);
        }
    } else if (sec == 3) {     // W2F e1
        if (idx < 65536) {
            int step = idx >> 13, q = step >> 1, kt2 = step & 1;
            int rem = idx & 8191;
            int cb = rem >> 10, ks = (rem >> 9) & 1, ln = (rem >> 3) & 63, j = rem & 7;
            int c = cb * 16 + (ln & 15);
            int k = q * 128 + kt2 * 64 + ks * 32 + (ln >> 4) * 8 + j;
            w2f_e1[l * 65536 + idx] = f2b(We1b[l * 65536 + k * 128 + c]);
        }
    } else if (sec == 4) {     // W1F e2
        if (idx < 65536) {
            int step = idx >> 13, q = step >> 1, kt = step & 1;
            int rem = idx & 8191;
            int nb = rem >> 10, ks = (rem >> 9) & 1, ln = (rem >> 3) & 63, j = rem & 7;
            int n = q * 128 + nb * 16 + (ln & 15);
            int k = kt * 64 + ks * 32 + (ln >> 4) * 8 + j;
            w1f_e2[l * 65536 + idx] = f2b(We2a[l * 65536 + k * 512 + n]);
        }
    } else {                   // W2F e2
        if (idx < 65536) {
            int step = idx >> 13, q = step >> 1, kt2 = step & 1;
            int rem = idx & 8191;
            int cb = rem >> 10, ks = (rem >> 9) & 1, ln = (rem >> 3) & 63, j = rem & 7;
            int c = cb * 16 + (ln & 15);
            int k = q * 128 + kt2 * 64 + ks * 32 + (ln >> 4) * 8 + j;
            w2f_e2[l * 65536 + idx] = f2b(We2b[l * 65536 + k * 128 + c]);
        }
    }
}

__global__ void init_e(const float4* __restrict__ src, ushort4* __restrict__ dst) {
    const long n4 = 8388608;
    for (long i = (long)blockIdx.x * blockDim.x + threadIdx.x; i < n4; i += (long)gridDim.x * blockDim.x) {
        float4 v = src[i];
        ushort4 o;
        o.x = f2b(v.x); o.y = f2b(v.y); o.z = f2b(v.z); o.w = f2b(v.w);
        dst[i] = o;
    }
}

__global__ void init_n(const float* __restrict__ node, float* __restrict__ nf) {
    int i = blockIdx.x * 256 + threadIdx.x;
    if (i < 131072) nf[i] = node[i];
}

// ---------------- pre_node ----------------
__launch_bounds__(512)
__global__ void pre_node_kernel(const float* __restrict__ nf, const float* __restrict__ We1a,
                                float* __restrict__ preS, float* __restrict__ preT) {
    __shared__ float nr[128];
    int tid = threadIdx.x;
    int row = blockIdx.x;
    if (tid < 128) nr[tid] = nf[(long)row * 128 + tid];
    __syncthreads();
    int c = tid;
    float s = 0.f, t = 0.f;
    const float* Ws = We1a + (long)256 * 512 + c;
    const float* Wt = We1a + (long)384 * 512 + c;
    #pragma unroll 8
    for (int k = 0; k < 128; ++k) {
        float nv = nr[k];
        s += nv * Ws[k * 512];
        t += nv * Wt[k * 512];
    }
    preS[(long)row * 512 + c] = s;
    preT[(long)row * 512 + c] = t;
}

// ---------------- K1: qn/vn ----------------
__global__ void qkvn_kernel(const float* __restrict__ nf, const float* __restrict__ W,
                            const float* __restrict__ bias, float* __restrict__ qn, float* __restrict__ vn) {
    __shared__ float nr[128];
    int tid = threadIdx.x;
    int row = blockIdx.x;
    if (tid < 128) nr[tid] = nf[(long)row * 128 + tid];
    __syncthreads();
    int c = tid & 127;
    bool isq = tid < 128;
    int col = (c >> 4) * 48 + (c & 15) + (isq ? 0 : 32);
    float a = bias[col];
    #pragma unroll 8
    for (int k = 0; k < 128; ++k) a += nr[k] * W[k * 384 + col];
    if (isq) qn[(long)row * 128 + c] = a;
    else     vn[(long)row * 128 + c] = a;
}

// ---------------- K2: scores (A via LDS, Wq fragments global->VGPR) ----------------
__launch_bounds__(256, 2)
__global__ void scores_kernel(const u16* __restrict__ ein, const u16* __restrict__ WqF,
                              const float* __restrict__ bqp, const float* __restrict__ qn,
                              float* __restrict__ scoresp) {
    __shared__ u16 As[128 * 64];
    int tid = threadIdx.x;
    int wid = tid >> 6, lane = tid & 63;
    int bid = blockIdx.x;
    int jhalf = bid & 1, bi = bid >> 1;
    int b = bi >> 8, i = bi & 255;
    int wr = wid >> 1, wc = wid & 1;

    f32x4 acc[4][4];
    f32x4 z = {0.f, 0.f, 0.f, 0.f};
    #pragma unroll
    for (int m = 0; m < 4; ++m)
        #pragma unroll
        for (int n = 0; n < 4; ++n) acc[m][n] = z;

    const u16* wq = WqF + (wc * 4) * 1024 + lane * 8;
    const long arow0 = ((long)(b * NN + i) * NN + jhalf * 128);
    for (int kt = 0; kt < 2; ++kt) {
        int k0 = kt << 6;
        #pragma unroll
        for (int p = 0; p < 4; ++p) {
            int r = p * 32 + (tid >> 3);
            int ch = tid & 7;
            const u16* src = ein + (arow0 + r) * 128 + k0 + ((ch ^ (r & 7)) << 3);
            glds16(src, (char*)As + (p << 12) + (wid << 10));
        }
        __syncthreads();
        #pragma unroll
        for (int ks = 0; ks < 2; ++ks) {
            bf16x8 af[4], bfr[4];
            #pragma unroll
            for (int m = 0; m < 4; ++m) {
                int r = wr * 64 + m * 16 + (lane & 15);
                int ch = (ks * 4 + (lane >> 4)) ^ (r & 7);
                af[m] = *reinterpret_cast<const bf16x8*>(&As[r * 64 + ch * 8]);
            }
            #pragma unroll
            for (int n = 0; n < 4; ++n)
                bfr[n] = *reinterpret_cast<const bf16x8*>(wq + kt * 8192 + n * 1024 + ks * 512);
            #pragma unroll
            for (int m = 0; m < 4; ++m)
                #pragma unroll
                for (int n = 0; n < 4; ++n)
                    acc[m][n] = __builtin_amdgcn_mfma_f32_16x16x32_bf16(af[m], bfr[n], acc[m][n], 0, 0, 0);
        }
        __syncthreads();
    }
    const float* qnb = qn + (long)(b * NN + i) * 128;
    #pragma unroll
    for (int m = 0; m < 4; ++m) {
        #pragma unroll
        for (int n = 0; n < 4; ++n) {
            int col = wc * 64 + n * 16 + (lane & 15);
            float add = bqp[col] + qnb[col];
            float sv[4];
            #pragma unroll
            for (int t = 0; t < 4; ++t) { float qv = acc[m][n][t] + add; sv[t] = qv * qv; }
            #pragma unroll
            for (int mk = 1; mk <= 8; mk <<= 1)
                #pragma unroll
                for (int t = 0; t < 4; ++t) sv[t] += __shfl_xor(sv[t], mk);
            if ((lane & 15) == 0) {
                int head = wc * 4 + n;
                int jb = jhalf * 128 + wr * 64 + m * 16 + ((lane >> 4) << 2);
                long sbase = ((long)(b * 8 + head) * 256 + i) * 256 + jb;
                #pragma unroll
                for (int t = 0; t < 4; ++t) scoresp[sbase + t] = sv[t] * 0.25f;
            }
        }
    }
}

// ---------------- K3: softmax + factored PV ----------------
__launch_bounds__(256)
__global__ void attn_pv_kernel(const float* __restrict__ scoresp, const u16* __restrict__ ein,
                               const float* __restrict__ vn, const u16* __restrict__ Wv,
                               const float* __restrict__ bvp, float* __restrict__ attn_o) {
    __shared__ float s_s[8 * 256];
    __shared__ float g_s[8 * 128];
    __shared__ float part[256];
    int tid = threadIdx.x;
    int b = blockIdx.x >> 8, i = blockIdx.x & 255;
    for (int v = tid; v < 2048; v += 256) {
        int h = v >> 8, j = v & 255;
        s_s[v] = scoresp[((long)(b * 8 + h) * 256 + i) * 256 + j];
    }
    __syncthreads();
    {
        int h = tid >> 5, lg = tid & 31;
        float vals[8], mx = -1e30f;
        #pragma unroll
        for (int t = 0; t < 8; ++t) { vals[t] = s_s[h * 256 + lg + t * 32]; mx = fmaxf(mx, vals[t]); }
        #pragma unroll
        for (int mk = 16; mk; mk >>= 1) mx = fmaxf(mx, __shfl_xor(mx, mk));
        float sum = 0.f;
        #pragma unroll
        for (int t = 0; t < 8; ++t) { vals[t] = __expf(vals[t] - mx); sum += vals[t]; }
        #pragma unroll
        for (int mk = 16; mk; mk >>= 1) sum += __shfl_xor(sum, mk);
        float inv = 1.f / sum;
        #pragma unroll
        for (int t = 0; t < 8; ++t) s_s[h * 256 + lg + t * 32] = vals[t] * inv;
    }
    __syncthreads();
    {
        int k = tid & 127, h0 = tid >> 7;
        const u16* erow = ein + ((long)(b * NN + i) * NN) * 128 + k;
        float a0 = 0, a1 = 0, a2 = 0, a3 = 0;
        for (int j = 0; j < 256; ++j) {
            float ev = b2f(erow[(long)j * 128]);
            a0 += s_s[(h0    ) * 256 + j] * ev;
            a1 += s_s[(h0 + 2) * 256 + j] * ev;
            a2 += s_s[(h0 + 4) * 256 + j] * ev;
            a3 += s_s[(h0 + 6) * 256 + j] * ev;
        }
        g_s[(h0    ) * 128 + k] = a0;
        g_s[(h0 + 2) * 128 + k] = a1;
        g_s[(h0 + 4) * 128 + k] = a2;
        g_s[(h0 + 6) * 128 + k] = a3;
    }
    __syncthreads();
    {
        int c = tid & 127, half = tid >> 7;
        int h = c >> 4;
        float a = 0.f;
        for (int j = half * 128; j < half * 128 + 128; ++j)
            a += s_s[h * 256 + j] * vn[((long)(b * NN + j)) * 128 + c];
        for (int k = half * 64; k < half * 64 + 64; ++k)
            a += g_s[h * 128 + k] * b2f(Wv[k * 128 + c]);
        part[tid] = a;
    }
    __syncthreads();
    if (tid < 128)
        attn_o[((long)(b * NN + i)) * 128 + tid] = part[tid] + part[128 + tid] + bvp[tid];
}

// ---------------- K4: node path (split-k on the two long serial chains) ----------------
__launch_bounds__(256)
__global__ void node_kernel(const float* __restrict__ attn_o, float* __restrict__ nf,
                            const float* __restrict__ Wo, const float* __restrict__ bo,
                            const float* __restrict__ Wn1, const float* __restrict__ bn1,
                            const float* __restrict__ Wn2, const float* __restrict__ bn2,
                            const float* __restrict__ g1, const float* __restrict__ b1,
                            const float* __restrict__ g2, const float* __restrict__ b2) {
    __shared__ float ao[128], nr[128], n1[128], hb[512];
    __shared__ float part[256];
    __shared__ float red[8];
    int tid = threadIdx.x;
    int wid = tid >> 6, lane = tid & 63;
    long base = (long)blockIdx.x * 128;
    if (tid < 128) { ao[tid] = attn_o[base + tid]; nr[tid] = nf[base + tid]; }
    __syncthreads();
    {   // Wo proj: split k across both halves
        int c = tid & 127, half = tid >> 7;
        float a = 0.f;
        #pragma unroll 8
        for (int k = half * 64; k < half * 64 + 64; ++k) a += ao[k] * Wo[k * 128 + c];
        part[tid] = a;
    }
    __syncthreads();
    float x = 0.f;
    if (tid < 128) x = nr[tid] + bo[tid] + part[tid] + part[128 + tid];
    float s = (tid < 128) ? x : 0.f, q = (tid < 128) ? x * x : 0.f;
    #pragma unroll
    for (int mk = 1; mk <= 32; mk <<= 1) { s += __shfl_xor(s, mk); q += __shfl_xor(q, mk); }
    if (lane == 0) { red[wid * 2] = s; red[wid * 2 + 1] = q; }
    __syncthreads();
    float sum = red[0] + red[2] + red[4] + red[6];
    float sq  = red[1] + red[3] + red[5] + red[7];
    float mean = sum * (1.f / 128.f);
    float var = sq * (1.f / 128.f) - mean * mean;
    float rs = rsqrtf(var + 1e-5f);
    __syncthreads();
    if (tid < 128) n1[tid] = (x - mean) * rs * g1[tid] + b1[tid];
    __syncthreads();
    for (int c = tid; c < 512; c += 256) {
        float a = bn1[c];
        #pragma unroll 8
        for (int k = 0; k < 128; ++k) a += n1[k] * Wn1[k * 512 + c];
        hb[c] = a > 0.f ? a : 0.f;
    }
    __syncthreads();
    {   // Wn2 proj: split k (512) across both halves
        int c = tid & 127, half = tid >> 7;
        float a = 0.f;
        #pragma unroll 8
        for (int k = half * 256; k < half * 256 + 256; ++k) a += hb[k] * Wn2[k * 128 + c];
        part[tid] = a;
    }
    __syncthreads();
    float y = 0.f;
    if (tid < 128) y = n1[tid] + bn2[tid] + part[tid] + part[128 + tid];
    float s2 = (tid < 128) ? y : 0.f, q2 = (tid < 128) ? y * y : 0.f;
    #pragma unroll
    for (int mk = 1; mk <= 32; mk <<= 1) { s2 += __shfl_xor(s2, mk); q2 += __shfl_xor(q2, mk); }
    if (lane == 0) { red[wid * 2] = s2; red[wid * 2 + 1] = q2; }
    __syncthreads();
    sum = red[0] + red[2] + red[4] + red[6];
    sq  = red[1] + red[3] + red[5] + red[7];
    mean = sum * (1.f / 128.f);
    var = sq * (1.f / 128.f) - mean * mean;
    rs = rsqrtf(var + 1e-5f);
    if (tid < 128) {
        float o = (y - mean) * rs * g2[tid] + b2[tid];
        nf[base + tid] = o;
    }
}

// ---------------- fused edge-MLP v6: BOTH edge MLPs in one kernel (R8/R14 verified best) ----------------
__launch_bounds__(256, 3)
__global__ void fused_mlp6(const u16* __restrict__ W1aF, const float* __restrict__ b1a,
                           const u16* __restrict__ W1bF, const float* __restrict__ b1b,
                           const u16* __restrict__ W2aF, const float* __restrict__ b2a,
                           const u16* __restrict__ W2bF, const float* __restrict__ b2b,
                           const u16* __restrict__ ein,
                           const float* __restrict__ preS, const float* __restrict__ preT,
                           const float* __restrict__ ln1g, const float* __restrict__ ln1b,
                           const float* __restrict__ ln2g, const float* __restrict__ ln2b,
                           u16* __restrict__ e_dst) {
    __shared__ __align__(16) u16 A_lds[16384];   // 4 regions x 4096 u16: 0,1 = e(i,j); 2,3 = e(j,i) -> e_mid
    __shared__ __align__(16) u16 Hs[8192];       // 16KB H tile [64r][128n] chunk-swizzled
    __shared__ float psum[256], psq[256];

    int tid = threadIdx.x;
    int wid = tid >> 6, lane = tid & 63;
    long row0 = (long)blockIdx.x * 64;
    int b = (int)(row0 >> 16);
    int rem0 = (int)(row0 & 65535);
    int i_ = rem0 >> 8, j0 = rem0 & 255;

    #pragma unroll
    for (int kt = 0; kt < 4; ++kt)
        #pragma unroll
        for (int pp = 0; pp < 2; ++pp) {
            int r = pp * 32 + (tid >> 3);
            int ch = tid & 7;
            long ridx = (kt < 2) ? (long)(b * NN + i_) * NN + (j0 + r)
                                 : (long)(b * NN + (j0 + r)) * NN + i_;
            const u16* src = ein + ridx * DD + ((kt & 1) << 6) + ((ch ^ (r & 7)) << 3);
            glds16(src, (char*)A_lds + kt * 8192 + (pp << 12) + (wid << 10));
        }
    asm volatile("s_waitcnt vmcnt(0)" ::: "memory");
    __builtin_amdgcn_sched_barrier(0);
    __builtin_amdgcn_s_barrier();
    __builtin_amdgcn_sched_barrier(0);

    const u16* w1a = W1aF + (wid * 2) * 1024 + lane * 8;
    const u16* w1b = W1bF + (wid * 2) * 1024 + lane * 8;
    const u16* w2a = W2aF + (wid * 2) * 1024 + lane * 8;
    const u16* w2b = W2bF + (wid * 2) * 1024 + lane * 8;

    f32x4 z = {0.f, 0.f, 0.f, 0.f};
    f32x4 acc1[2][4], acc2[4][2];
    bf16x8 afA[4], afB[4], g2A[4], g2B[4];

    auto FR4 = [&](bf16x8 (&d)[4], const u16* base, int step) {
        const u16* p = base + (step << 13);
        d[0] = *reinterpret_cast<const bf16x8*>(p);
        d[1] = *reinterpret_cast<const bf16x8*>(p + 1024);
        d[2] = *reinterpret_cast<const bf16x8*>(p + 512);
        d[3] = *reinterpret_cast<const bf16x8*>(p + 1536);
    };
    auto G1K = [&](bf16x8 (&cur)[4], int reg) {
        #pragma unroll
        for (int ks = 0; ks < 2; ++ks) {
            bf16x8 bfr[4];
            #pragma unroll
            for (int rf = 0; rf < 4; ++rf) {
                int r = rf * 16 + (lane & 15);
                int ch = (ks * 4 + (lane >> 4)) ^ (r & 7);
                bfr[rf] = *reinterpret_cast<const bf16x8*>(&A_lds[reg * 4096 + r * 64 + ch * 8]);
            }
            #pragma unroll
            for (int mn = 0; mn < 2; ++mn)
                #pragma unroll
                for (int rf = 0; rf < 4; ++rf)
                    acc1[mn][rf] = __builtin_amdgcn_mfma_f32_16x16x32_bf16(cur[ks * 2 + mn], bfr[rf], acc1[mn][rf], 0, 0, 0);
        }
    };
    auto G2K = [&](bf16x8 (&w)[4], int kt2) {
        #pragma unroll
        for (int ks = 0; ks < 2; ++ks) {
            bf16x8 af2[4];
            #pragma unroll
            for (int rf = 0; rf < 4; ++rf) {
                int r = rf * 16 + (lane & 15);
                int c8 = kt2 * 8 + ks * 4 + (lane >> 4);
                int cs = (c8 & 8) | ((c8 ^ r) & 7);
                af2[rf] = *reinterpret_cast<const bf16x8*>((const char*)Hs + r * 256 + cs * 16);
            }
            #pragma unroll
            for (int rf = 0; rf < 4; ++rf)
                #pragma unroll
                for (int cf = 0; cf < 2; ++cf)
                    acc2[rf][cf] = __builtin_amdgcn_mfma_f32_16x16x32_bf16(af2[rf], w[ks * 2 + cf], acc2[rf][cf], 0, 0, 0);
        }
    };
    auto EPI = [&](int q, const float* bias, bool wp) {
        #pragma unroll
        for (int mn = 0; mn < 2; ++mn) {
            int nl0 = wid * 32 + mn * 16 + ((lane >> 4) << 2);
            int n0g = (q << 7) + nl0;
            float4 bb = *reinterpret_cast<const float4*>(&bias[n0g]);
            if (wp) {
                float4 pt = *reinterpret_cast<const float4*>(&preT[(long)(b * NN + i_) * 512 + n0g]);
                bb.x += pt.x; bb.y += pt.y; bb.z += pt.z; bb.w += pt.w;
            }
            #pragma unroll
            for (int rf = 0; rf < 4; ++rf) {
                int r = rf * 16 + (lane & 15);
                float b0 = bb.x, b1_ = bb.y, b2_ = bb.z, b3 = bb.w;
                if (wp) {
                    float4 ps = *reinterpret_cast<const float4*>(&preS[(long)(b * NN + j0 + r) * 512 + n0g]);
                    b0 += ps.x; b1_ += ps.y; b2_ += ps.z; b3 += ps.w;
                }
                float v0 = acc1[mn][rf][0] + b0; v0 = v0 > 0.f ? v0 : 0.f;
                float v1 = acc1[mn][rf][1] + b1_; v1 = v1 > 0.f ? v1 : 0.f;
                float v2 = acc1[mn][rf][2] + b2_; v2 = v2 > 0.f ? v2 : 0.f;
                float v3 = acc1[mn][rf][3] + b3; v3 = v3 > 0.f ? v3 : 0.f;
                uint2 pk;
                pk.x = pk2(v0, v1);
                pk.y = pk2(v2, v3);
                int c8 = nl0 >> 3;
                int cs = (c8 & 8) | ((c8 ^ r) & 7);
                *reinterpret_cast<uint2*>((char*)Hs + r * 256 + cs * 16 + (nl0 & 7) * 2) = pk;
            }
        }
    };
    auto LNA = [&](const float* bias, int rb) {
        #pragma unroll
        for (int rf = 0; rf < 4; ++rf) {
            float sv[4] = {0.f, 0.f, 0.f, 0.f}, qv[4] = {0.f, 0.f, 0.f, 0.f};
            #pragma unroll
            for (int cf = 0; cf < 2; ++cf) {
                int c = wid * 32 + cf * 16 + (lane & 15);
                float bb = bias[c];
                int kk = c & 63, kreg = rb + (c >> 6);
                #pragma unroll
                for (int t = 0; t < 4; ++t) {
                    int r = rf * 16 + ((lane >> 4) << 2) + t;
                    float er = b2f(A_lds[kreg * 4096 + r * 64 + (((kk >> 3) ^ (r & 7)) << 3) + (kk & 7)]);
                    float x = acc2[rf][cf][t] + bb + er;
                    acc2[rf][cf][t] = x;
                    sv[t] += x;
                    qv[t] += x * x;
                }
            }
            #pragma unroll
            for (int mk = 1; mk <= 8; mk <<= 1)
                #pragma unroll
                for (int t = 0; t < 4; ++t) { sv[t] += __shfl_xor(sv[t], mk); qv[t] += __shfl_xor(qv[t], mk); }
            if ((lane & 15) == 0) {
                #pragma unroll
                for (int t = 0; t < 4; ++t) {
                    int r = rf * 16 + ((lane >> 4) << 2) + t;
                    psum[r * 4 + wid] = sv[t];
                    psq[r * 4 + wid] = qv[t];
                }
            }
        }
    };

    // ============================= MLP1 =============================
    #pragma unroll
    for (int rf = 0; rf < 4; ++rf) { acc2[rf][0] = z; acc2[rf][1] = z; }
    FR4(afA, w1a, 0);
    for (int q = 0; q < 4; ++q) {
        #pragma unroll
        for (int mn = 0; mn < 2; ++mn)
            #pragma unroll
            for (int rf = 0; rf < 4; ++rf) acc1[mn][rf] = z;
        FR4(afB, w1a, q * 4 + 1); G1K(afA, 0);
        FR4(afA, w1a, q * 4 + 2); G1K(afB, 1);
        FR4(afB, w1a, q * 4 + 3); G1K(afA, 2);
        G1K(afB, 3);
        FR4(g2A, w1b, q * 2 + 0);
        if (q) {
            __builtin_amdgcn_sched_barrier(0);
            __builtin_amdgcn_s_barrier();
            __builtin_amdgcn_sched_barrier(0);
        }
        EPI(q, b1a, true);
        asm volatile("s_waitcnt lgkmcnt(0)" ::: "memory");
        __builtin_amdgcn_sched_barrier(0);
        __builtin_amdgcn_s_barrier();
        __builtin_amdgcn_sched_barrier(0);
        FR4(g2B, w1b, q * 2 + 1);
        G2K(g2A, 0);
        if (q < 3) FR4(afA, w1a, (q + 1) * 4);
        G2K(g2B, 1);
    }

    // ---- LN1 -> e_mid into regions 2,3 ----
    LNA(b1b, 0);
    __syncthreads();
    #pragma unroll
    for (int rf = 0; rf < 4; ++rf) {
        #pragma unroll
        for (int t = 0; t < 4; ++t) {
            int r = rf * 16 + ((lane >> 4) << 2) + t;
            float sum = psum[r * 4] + psum[r * 4 + 1] + psum[r * 4 + 2] + psum[r * 4 + 3];
            float sq  = psq[r * 4] + psq[r * 4 + 1] + psq[r * 4 + 2] + psq[r * 4 + 3];
            float mean = sum * (1.f / 128.f);
            float var = sq * (1.f / 128.f) - mean * mean;
            float rs = rsqrtf(var + 1e-5f);
            #pragma unroll
            for (int cf = 0; cf < 2; ++cf) {
                int c = wid * 32 + cf * 16 + (lane & 15);
                float o = (acc2[rf][cf][t] - mean) * rs * ln1g[c] + ln1b[c];
                int kk = c & 63;
                A_lds[(2 + (c >> 6)) * 4096 + r * 64 + (((kk >> 3) ^ (r & 7)) << 3) + (kk & 7)] = b16(o);
            }
        }
    }
    __syncthreads();

    // ============================= MLP2 =============================
    #pragma unroll
    for (int rf = 0; rf < 4; ++rf) { acc2[rf][0] = z; acc2[rf][1] = z; }
    FR4(afA, w2a, 0);
    for (int q = 0; q < 4; ++q) {
        #pragma unroll
        for (int mn = 0; mn < 2; ++mn)
            #pragma unroll
            for (int rf = 0; rf < 4; ++rf) acc1[mn][rf] = z;
        FR4(afB, w2a, q * 2 + 1); G1K(afA, 2);
        G1K(afB, 3);
        FR4(g2A, w2b, q * 2 + 0);
        if (q) {
            __builtin_amdgcn_sched_barrier(0);
            __builtin_amdgcn_s_barrier();
            __builtin_amdgcn_sched_barrier(0);
        }
        EPI(q, b2a, false);
        asm volatile("s_waitcnt lgkmcnt(0)" ::: "memory");
        __builtin_amdgcn_sched_barrier(0);
        __builtin_amdgcn_s_barrier();
        __builtin_amdgcn_sched_barrier(0);
        FR4(g2B, w2b, q * 2 + 1);
        G2K(g2A, 0);
        if (q < 3) FR4(afA, w2a, (q + 1) * 2);
        G2K(g2B, 1);
    }

    // ---- LN2 (e_res = e_mid, regions 2,3) -> repack into regions 0,1 linear ----
    LNA(b2b, 2);
    __syncthreads();
    #pragma unroll
    for (int rf = 0; rf < 4; ++rf) {
        #pragma unroll
        for (int t = 0; t < 4; ++t) {
            int r = rf * 16 + ((lane >> 4) << 2) + t;
            float sum = psum[r * 4] + psum[r * 4 + 1] + psum[r * 4 + 2] + psum[r * 4 + 3];
            float sq  = psq[r * 4] + psq[r * 4 + 1] + psq[r * 4 + 2] + psq[r * 4 + 3];
            float mean = sum * (1.f / 128.f);
            float var = sq * (1.f / 128.f) - mean * mean;
            float rs = rsqrtf(var + 1e-5f);
            #pragma unroll
            for (int cf = 0; cf < 2; ++cf) {
                int c = wid * 32 + cf * 16 + (lane & 15);
                float o = (acc2[rf][cf][t] - mean) * rs * ln2g[c] + ln2b[c];
                A_lds[r * 128 + c] = b16(o);
            }
        }
    }
    __syncthreads();
    #pragma unroll
    for (int pp = 0; pp < 4; ++pp) {
        ulonglong2 v = *reinterpret_cast<const ulonglong2*>((char*)A_lds + (pp << 12) + tid * 16);
        *reinterpret_cast<ulonglong2*>((char*)e_dst + row0 * 256 + (pp << 12) + tid * 16) = v;
    }
}

extern "C" void kernel_launch(void* const* d_in, const int* in_sizes, int n_in,
                              void* d_out, int out_size, void* d_ws, size_t ws_size,
                              hipStream_t stream) {
    (void)in_sizes; (void)n_in; (void)out_size; (void)ws_size;
    const float* node   = (const float*)d_in[0];
    const float* edge   = (const float*)d_in[1];
    const float* Wqkv_n = (const float*)d_in[2];
    const float* bqkv_n = (const float*)d_in[3];
    const float* Wqkv_e = (const float*)d_in[4];
    const float* bqkv_e = (const float*)d_in[5];
    const float* Wo     = (const float*)d_in[6];
    const float* bo     = (const float*)d_in[7];
    const float* Wn1    = (const float*)d_in[8];
    const float* bn1    = (const float*)d_in[9];
    const float* Wn2    = (const float*)d_in[10];
    const float* bn2    = (const float*)d_in[11];
    const float* ln1n_g = (const float*)d_in[12];
    const float* ln1n_b = (const float*)d_in[13];
    const float* ln2n_g = (const float*)d_in[14];
    const float* ln2n_b = (const float*)d_in[15];
    const float* We1a   = (const float*)d_in[16];
    const float* be1a   = (const float*)d_in[17];
    const float* We1b   = (const float*)d_in[18];
    const float* be1b   = (const float*)d_in[19];
    const float* We2a   = (const float*)d_in[20];
    const float* be2a   = (const float*)d_in[21];
    const float* We2b   = (const float*)d_in[22];
    const float* be2b   = (const float*)d_in[23];
    const float* ln1e_g = (const float*)d_in[24];
    const float* ln1e_b = (const float*)d_in[25];
    const float* ln2e_g = (const float*)d_in[26];
    const float* ln2e_b = (const float*)d_in[27];

    size_t off = 0;
    char* wsb = (char*)d_ws;
    auto alloc = [&](size_t bytes) -> void* {
        void* p = wsb + off;
        off = (off + bytes + 255) & ~(size_t)255;
        return p;
    };
    u16* eb0      = (u16*)alloc((size_t)RNN * 128 * 2);
    u16* eb1      = (u16*)alloc((size_t)RNN * 128 * 2);
    float* scoresp= (float*)alloc((size_t)2097152 * 4);
    float* qn     = (float*)alloc(131072 * 4);
    float* vn     = (float*)alloc(131072 * 4);
    float* attn_o = (float*)alloc(131072 * 4);
    float* nf     = (float*)alloc(131072 * 4);
    float* preS   = (float*)alloc((size_t)1024 * 512 * 4);
    float* preT   = (float*)alloc((size_t)1024 * 512 * 4);
    u16* wqF      = (u16*)alloc(3 * 16384 * 2);
    u16* wv       = (u16*)alloc(3 * 16384 * 2);
    float* bqp    = (float*)alloc(3 * 128 * 4);
    float* bvp    = (float*)alloc(3 * 128 * 4);
    u16* w1f_e1   = (u16*)alloc(3 * 131072ull * 2);
    u16* w2f_e1   = (u16*)alloc(3 * 65536 * 2);
    u16* w1f_e2   = (u16*)alloc(3 * 65536 * 2);
    u16* w2f_e2   = (u16*)alloc(3 * 65536 * 2);

    {
        dim3 g(512, 6, 3);
        prep_weights<<<g, 256, 0, stream>>>(Wqkv_e, bqkv_e, We1a, We1b, We2a, We2b,
                                            wqF, wv, bqp, bvp, w1f_e1, w2f_e1, w1f_e2, w2f_e2);
    }
    init_e<<<2048, 256, 0, stream>>>((const float4*)edge, (ushort4*)eb0);
    init_n<<<512, 256, 0, stream>>>(node, nf);

    for (int l = 0; l < 3; ++l) {
        u16* ein  = (l & 1) ? eb1 : eb0;
        u16* eout = (l & 1) ? eb0 : eb1;
        qkvn_kernel<<<1024, 256, 0, stream>>>(nf, Wqkv_n + l * 49152, bqkv_n + l * 384, qn, vn);
        scores_kernel<<<2048, 256, 0, stream>>>(ein, wqF + l * 16384, bqp + l * 128, qn, scoresp);
        attn_pv_kernel<<<1024, 256, 0, stream>>>(scoresp, ein, vn, wv + l * 16384, bvp + l * 128, attn_o);
        node_kernel<<<1024, 256, 0, stream>>>(attn_o, nf,
                                              Wo + l * 16384, bo + l * 128,
                                              Wn1 + l * 65536, bn1 + l * 512,
                                              Wn2 + l * 65536, bn2 + l * 128,
                                              ln1n_g + l * 128, ln1n_b + l * 128,
                                              ln2n_g + l * 128, ln2n_b + l * 128);
        pre_node_kernel<<<1024, 512, 0, stream>>>(nf, We1a + (size_t)l * 262144, preS, preT);
        fused_mlp6<<<4096, 256, 0, stream>>>(w1f_e1 + l * 131072, be1a + l * 512,
                                             w2f_e1 + l * 65536, be1b + l * 128,
                                             w1f_e2 + l * 65536, be2a + l * 512,
                                             w2f_e2 + l * 65536, be2b + l * 128,
                                             ein, preS, preT,
                                             ln1e_g + l * 128, ln1e_b + l * 128,
                                             ln2e_g + l * 128, ln2e_b + l * 128,
                                             eout);
    }
    hipMemcpyAsync(d_out, nf, 131072 * sizeof(float), hipMemcpyDeviceToDevice, stream);
}